// Round 8
// baseline (271.600 us; speedup 1.0000x reference)
//
#include <hip/hip_runtime.h>

// Attention_29583734734990 : resid[4,2048,1024] f32, w_q/k/v[16,1024,64], w_o[16,64,1024]
// out[4,2048,1024] f32.  bf16 MFMA pipeline (threshold is bf16-floor 3.14e-2).

typedef __attribute__((ext_vector_type(8))) short short8;
typedef __attribute__((ext_vector_type(4))) float f32x4;
typedef __attribute__((ext_vector_type(16))) float f32x16;

#define GLDS16(g, l) __builtin_amdgcn_global_load_lds(                        \
    (const __attribute__((address_space(1))) unsigned int*)(g),               \
    (__attribute__((address_space(3))) unsigned int*)(l), 16, 0, 0)

static __device__ __forceinline__ unsigned short f2b(float f) {
  union { float f; unsigned u; } c; c.f = f;
  unsigned r = c.u + 0x7fffu + ((c.u >> 16) & 1u);
  return (unsigned short)(r >> 16);
}

// ---------------- cast resid f32 -> bf16, row-major [8192][1024] ----------------
__global__ void k_cast(const float* __restrict__ x, unsigned short* __restrict__ o, int n4) {
  int i = blockIdx.x * blockDim.x + threadIdx.x;
  if (i >= n4) return;
  float4 v = reinterpret_cast<const float4*>(x)[i];
  ushort4 u;
  u.x = f2b(v.x); u.y = f2b(v.y); u.z = f2b(v.z); u.w = f2b(v.w);
  reinterpret_cast<ushort4*>(o)[i] = u;
}

// ---- w_q/w_k/w_v [16][1024][64] f32 -> W3t[(which*1024 + h*64 + d)][1024 m] bf16 ----
__global__ void k_trans_qkv(const float* __restrict__ wq, const float* __restrict__ wk,
                            const float* __restrict__ wv, unsigned short* __restrict__ o) {
  __shared__ float t[64][65];
  int blk = blockIdx.x;            // 3*16*16
  int mt = blk & 15;
  int h = (blk >> 4) & 15;
  int which = blk >> 8;
  const float* w = which == 0 ? wq : (which == 1 ? wk : wv);
  int tid = threadIdx.x;
  int m0 = mt * 64;
  #pragma unroll
  for (int rep = 0; rep < 16; ++rep) {
    int idx = rep * 256 + tid;
    int r = idx >> 6, c = idx & 63;                 // r: m-offset, c: d
    t[r][c] = w[(h * 1024 + m0 + r) * 64 + c];
  }
  __syncthreads();
  #pragma unroll
  for (int rep = 0; rep < 16; ++rep) {
    int idx = rep * 256 + tid;
    int dr = idx >> 6, mc = idx & 63;               // dr: d, mc: m-offset
    o[(which * 1024 + h * 64 + dr) * 1024 + m0 + mc] = f2b(t[mc][dr]);
  }
}

// ---- w_o [1024 k][1024 m] f32 -> WoT[m][k] bf16 ----
__global__ void k_trans_wo(const float* __restrict__ wo, unsigned short* __restrict__ o) {
  __shared__ float t[64][65];
  int blk = blockIdx.x;            // 256
  int mt = blk & 15, kt = blk >> 4;
  int tid = threadIdx.x;
  int k0 = kt * 64, m0 = mt * 64;
  #pragma unroll
  for (int rep = 0; rep < 16; ++rep) {
    int idx = rep * 256 + tid;
    int r = idx >> 6, c = idx & 63;                 // r: k-offset, c: m-offset
    t[r][c] = wo[(k0 + r) * 1024 + m0 + c];
  }
  __syncthreads();
  #pragma unroll
  for (int rep = 0; rep < 16; ++rep) {
    int idx = rep * 256 + tid;
    int r = idx >> 6, c = idx & 63;                 // r: m-offset, c: k-offset
    o[(m0 + r) * 1024 + k0 + c] = f2b(t[c][r]);
  }
}

// ---------------- 128x128 bf16 GEMM -> Q/K/Vt (fused N=3072) ----------------
// Q outputs are PRE-SCALED by 1/sqrt(64)*log2(e) so attention scores are exp2-ready.
__global__ __launch_bounds__(256) void k_gemm_qkv(const unsigned short* __restrict__ A,
                                                  const unsigned short* __restrict__ Bt,
                                                  unsigned short* __restrict__ Qb,
                                                  unsigned short* __restrict__ Kb,
                                                  unsigned short* __restrict__ Vt) {
  __shared__ unsigned short As[128 * 32];
  __shared__ unsigned short Bs[128 * 32];
  const int bm = blockIdx.x, bn = blockIdx.y;
  const int tid = threadIdx.x;
  const int lane = tid & 63, wid = tid >> 6;
  const int wr = wid >> 1, wc = wid & 1;
  const int fr = lane & 15, fq = lane >> 4;

  f32x4 acc[4][4];
  #pragma unroll
  for (int i = 0; i < 4; ++i)
    #pragma unroll
    for (int n = 0; n < 4; ++n) acc[i][n] = f32x4{0.f, 0.f, 0.f, 0.f};

  const int arow = tid >> 2, acol = (tid & 3) * 8;
  const int lds0 = tid * 8, lds1 = (tid + 256) * 8;   // element offsets
  const unsigned short* aG0 = A + (bm * 128 + arow) * 1024 + acol;
  const unsigned short* aG1 = A + (bm * 128 + arow + 64) * 1024 + acol;
  const unsigned short* bG0 = Bt + (bn * 128 + arow) * 1024 + acol;
  const unsigned short* bG1 = Bt + (bn * 128 + arow + 64) * 1024 + acol;

  const unsigned short* Ar = As + (wr * 64 + fr) * 32 + fq * 8;
  const unsigned short* Br = Bs + (wc * 64 + fr) * 32 + fq * 8;

  for (int k0 = 0; k0 < 1024; k0 += 32) {
    __syncthreads();
    GLDS16(aG0 + k0, As + lds0);
    GLDS16(aG1 + k0, As + lds1);
    GLDS16(bG0 + k0, Bs + lds0);
    GLDS16(bG1 + k0, Bs + lds1);
    asm volatile("s_waitcnt vmcnt(0)" ::: "memory");
    __syncthreads();
    short8 a[4], b[4];
    #pragma unroll
    for (int i = 0; i < 4; ++i) a[i] = *reinterpret_cast<const short8*>(Ar + i * 512);
    #pragma unroll
    for (int n = 0; n < 4; ++n) b[n] = *reinterpret_cast<const short8*>(Br + n * 512);
    #pragma unroll
    for (int i = 0; i < 4; ++i)
      #pragma unroll
      for (int n = 0; n < 4; ++n)
        acc[i][n] = __builtin_amdgcn_mfma_f32_16x16x32_bf16(a[i], b[n], acc[i][n], 0, 0, 0);
  }

  const float CS = 0.125f * 1.44269504088896340736f;
  const int colb = bn * 128 + wc * 64 + fr;
  const int rowb = bm * 128 + wr * 64 + fq * 4;
  #pragma unroll
  for (int n = 0; n < 4; ++n) {
    const int col = colb + n * 16;
    const int which = col >> 10, rc = col & 1023;
    const int h = rc >> 6, d = rc & 63;
    #pragma unroll
    for (int i = 0; i < 4; ++i) {
      const int row = rowb + i * 16;
      const int b_ = row >> 11, s = row & 2047;
      if (which == 2) {
        ushort4 v;
        v.x = f2b(acc[i][n][0]); v.y = f2b(acc[i][n][1]);
        v.z = f2b(acc[i][n][2]); v.w = f2b(acc[i][n][3]);
        *reinterpret_cast<ushort4*>(&Vt[(((b_ * 16 + h) * 64) + d) * 2048 + s]) = v;
      } else {
        const float sc = (which == 0) ? CS : 1.f;
        unsigned short* dst = (which == 0 ? Qb : Kb) + ((b_ * 16 + h) * 2048 + s) * 64 + d;
        #pragma unroll
        for (int j = 0; j < 4; ++j) dst[j * 64] = f2b(acc[i][n][j] * sc);
      }
    }
  }
}

// ---------------- causal flash attention, swapped-QK^T 32x32 ----------------
// 2 waves/block share one tile-pair (p, 63-p): wave0 = tileA(p) full [p+1 chunks]
// + tileB first 31-p chunks; wave1 = tileB last 33 chunks. Partials combined via
// LDS after a CONVERGENT __syncthreads (no max-tracking -> pure sum).
// 4096 waves = 4/SIMD at <=128 VGPR.

static __device__ __forceinline__ f32x16 mfma32(short8 a, short8 b, f32x16 c) {
  return __builtin_amdgcn_mfma_f32_32x32x16_bf16(a, b, c, 0, 0, 0);
}

struct KV { short8 k0, k1, k2, k3, v0, v1, v2, v3; };

static __device__ __forceinline__ KV load_kv(const unsigned short* __restrict__ Kbh,
                                             const unsigned short* __restrict__ Vbh,
                                             int k0, int q, int hi) {
  KV r;
  const unsigned short* Kp = Kbh + (size_t)(k0 + q) * 64 + hi * 8;
  r.k0 = *reinterpret_cast<const short8*>(Kp);
  r.k1 = *reinterpret_cast<const short8*>(Kp + 16);
  r.k2 = *reinterpret_cast<const short8*>(Kp + 32);
  r.k3 = *reinterpret_cast<const short8*>(Kp + 48);
  const unsigned short* Vp = Vbh + (size_t)q * 2048 + k0 + hi * 8;
  r.v0 = *reinterpret_cast<const short8*>(Vp);
  r.v1 = *reinterpret_cast<const short8*>(Vp + 16);
  r.v2 = *reinterpret_cast<const short8*>(Vp + 32 * 2048);
  r.v3 = *reinterpret_cast<const short8*>(Vp + 32 * 2048 + 16);
  return r;
}

template<bool MASKED>
static __device__ __forceinline__ void tile_step(const KV& kv, int q, int hi,
    const short8& Qf0, const short8& Qf1, const short8& Qf2, const short8& Qf3,
    f32x16& accA, f32x16& accB, float& lsum) {
  f32x16 s = {0.f,0.f,0.f,0.f,0.f,0.f,0.f,0.f,0.f,0.f,0.f,0.f,0.f,0.f,0.f,0.f};
  s = mfma32(kv.k0, Qf0, s);
  s = mfma32(kv.k1, Qf1, s);
  s = mfma32(kv.k2, Qf2, s);
  s = mfma32(kv.k3, Qf3, s);

  float p[16];
  #pragma unroll
  for (int r = 0; r < 16; ++r) {
    if (MASKED) {
      const int kr = (r & 3) + 8 * (r >> 2) + 4 * hi;
      p[r] = (kr <= q) ? __builtin_amdgcn_exp2f(s[r]) : 0.f;
    } else {
      p[r] = __builtin_amdgcn_exp2f(s[r]);
    }
  }
  // tree sum
  float t0 = (p[0] + p[1]) + (p[2] + p[3]);
  float t1 = (p[4] + p[5]) + (p[6] + p[7]);
  float t2 = (p[8] + p[9]) + (p[10] + p[11]);
  float t3 = (p[12] + p[13]) + (p[14] + p[15]);
  lsum += (t0 + t1) + (t2 + t3);

  unsigned W[8], X[8];
  #pragma unroll
  for (int i = 0; i < 8; ++i)
    asm("v_cvt_pk_bf16_f32 %0, %1, %2" : "=v"(W[i]) : "v"(p[2 * i]), "v"(p[2 * i + 1]));
  #pragma unroll
  for (int i = 0; i < 8; ++i) X[i] = __shfl_xor(W[i], 32);

  union { unsigned u[4]; short8 v; } fa0, fa1;
  fa0.u[0] = hi ? X[2] : W[0];
  fa0.u[1] = hi ? X[3] : W[1];
  fa0.u[2] = hi ? W[2] : X[0];
  fa0.u[3] = hi ? W[3] : X[1];
  fa1.u[0] = hi ? X[6] : W[4];
  fa1.u[1] = hi ? X[7] : W[5];
  fa1.u[2] = hi ? W[6] : X[4];
  fa1.u[3] = hi ? W[7] : X[5];

  accA = mfma32(fa0.v, kv.v0, accA);
  accA = mfma32(fa1.v, kv.v1, accA);
  accB = mfma32(fa0.v, kv.v2, accB);
  accB = mfma32(fa1.v, kv.v3, accB);
}

// Process chunks [c0, c0+n) of 32 k each; last chunk optionally causal-masked.
// Rotate-by-2 register prefetch. Requires n >= 1.
template<bool MASK_LAST>
static __device__ __forceinline__ void run_span(
    const unsigned short* __restrict__ Kbh, const unsigned short* __restrict__ Vbh,
    int c0, int n, int q, int hi,
    const short8& Qf0, const short8& Qf1, const short8& Qf2, const short8& Qf3,
    f32x16& a0, f32x16& a1, float& l) {
  const int clast = c0 + n - 1;
  int c = c0;
  KV ca = load_kv(Kbh, Vbh, 32 * c, q, hi);
  while (clast - c >= 2) {
    KV cb = load_kv(Kbh, Vbh, 32 * (c + 1), q, hi);
    tile_step<false>(ca, q, hi, Qf0, Qf1, Qf2, Qf3, a0, a1, l);
    ca = load_kv(Kbh, Vbh, 32 * (c + 2), q, hi);
    tile_step<false>(cb, q, hi, Qf0, Qf1, Qf2, Qf3, a0, a1, l);
    c += 2;
  }
  if (c < clast) {
    KV cb = load_kv(Kbh, Vbh, 32 * (c + 1), q, hi);
    tile_step<false>(ca, q, hi, Qf0, Qf1, Qf2, Qf3, a0, a1, l);
    ca = cb;
    c += 1;
  }
  tile_step<MASK_LAST>(ca, q, hi, Qf0, Qf1, Qf2, Qf3, a0, a1, l);
}

static __device__ __forceinline__ void store_tile(unsigned short* __restrict__ Zb,
    int b_, int h, int q0, int q, int hi,
    const f32x16& a0, const f32x16& a1, float lsum) {
  const float lt = lsum + __shfl_xor(lsum, 32);
  const float rl = 1.f / lt;
  #pragma unroll
  for (int r = 0; r < 16; ++r) {
    const int qr = (r & 3) + 8 * (r >> 2) + 4 * hi;
    const float rlr = __shfl(rl, qr);
    unsigned short* dst = Zb + ((size_t)(b_ * 2048 + q0 + qr)) * 1024 + h * 64 + q;
    dst[0]  = f2b(a0[r] * rlr);
    dst[32] = f2b(a1[r] * rlr);
  }
}

__global__ __launch_bounds__(128, 4) void k_attn(const unsigned short* __restrict__ Qb,
                                                 const unsigned short* __restrict__ Kb,
                                                 const unsigned short* __restrict__ Vt,
                                                 unsigned short* __restrict__ Zb) {
  __shared__ float lds_acc[64][33];
  __shared__ float lds_l[64];
  const int lane = threadIdx.x & 63, w = threadIdx.x >> 6;   // w in {0,1}
  const int q = lane & 31, hi = lane >> 5;
  // XCD-pinned decode: bid%8 = XCD (round-robin); all 32 blocks of a bh share an XCD.
  const int bid = blockIdx.x;                    // 0..2047
  const int bh = (bid & 7) * 8 + ((bid >> 3) & 7);
  const int p = bid >> 6;                        // 0..31 : tile pair index
  const int q0A = 32 * p, q0B = 32 * (63 - p);
  const int b_ = bh >> 4, h = bh & 15;

  const unsigned short* Qbh = Qb + (size_t)bh * 2048 * 64;
  const unsigned short* Kbh = Kb + (size_t)bh * 2048 * 64;
  const unsigned short* Vbh = Vt + (size_t)bh * 64 * 2048;

  const f32x16 zero = {0.f,0.f,0.f,0.f,0.f,0.f,0.f,0.f,0.f,0.f,0.f,0.f,0.f,0.f,0.f,0.f};
  f32x16 a0 = zero, a1 = zero;   // tile-B accumulator (both waves)
  float l = 0.f;

  if (w == 0) {
    // ---- tile A (q0A), full: chunks [0, p] with masked end ----
    {
      const unsigned short* Qp = Qbh + (size_t)(q0A + q) * 64 + hi * 8;
      const short8 Qf0 = *reinterpret_cast<const short8*>(Qp);
      const short8 Qf1 = *reinterpret_cast<const short8*>(Qp + 16);
      const short8 Qf2 = *reinterpret_cast<const short8*>(Qp + 32);
      const short8 Qf3 = *reinterpret_cast<const short8*>(Qp + 48);
      f32x16 aa0 = zero, aa1 = zero;
      float la = 0.f;
      run_span<true>(Kbh, Vbh, 0, p + 1, q, hi, Qf0, Qf1, Qf2, Qf3, aa0, aa1, la);
      store_tile(Zb, b_, h, q0A, q, hi, aa0, aa1, la);
    }
    // ---- tile B (q0B), partial: chunks [0, 31-p), unmasked -> LDS ----
    {
      const unsigned short* Qp = Qbh + (size_t)(q0B + q) * 64 + hi * 8;
      const short8 Qf0 = *reinterpret_cast<const short8*>(Qp);
      const short8 Qf1 = *reinterpret_cast<const short8*>(Qp + 16);
      const short8 Qf2 = *reinterpret_cast<const short8*>(Qp + 32);
      const short8 Qf3 = *reinterpret_cast<const short8*>(Qp + 48);
      const int n = 31 - p;
      if (n > 0)
        run_span<false>(Kbh, Vbh, 0, n, q, hi, Qf0, Qf1, Qf2, Qf3, a0, a1, l);
      #pragma unroll
      for (int i = 0; i < 16; ++i) {
        lds_acc[lane][i] = a0[i];
        lds_acc[lane][16 + i] = a1[i];
      }
      lds_l[lane] = l;
    }
  } else {
    // ---- tile B (q0B), chunks [31-p, 64-p) = 33 chunks, masked end -> regs ----
    const unsigned short* Qp = Qbh + (size_t)(q0B + q) * 64 + hi * 8;
    const short8 Qf0 = *reinterpret_cast<const short8*>(Qp);
    const short8 Qf1 = *reinterpret_cast<const short8*>(Qp + 16);
    const short8 Qf2 = *reinterpret_cast<const short8*>(Qp + 32);
    const short8 Qf3 = *reinterpret_cast<const short8*>(Qp + 48);
    run_span<true>(Kbh, Vbh, 31 - p, 33, q, hi, Qf0, Qf1, Qf2, Qf3, a0, a1, l);
  }

  __syncthreads();   // CONVERGENT barrier: wave0's LDS partials now visible

  if (w == 1) {
    #pragma unroll
    for (int i = 0; i < 16; ++i) {
      a0[i] += lds_acc[lane][i];
      a1[i] += lds_acc[lane][16 + i];
    }
    l += lds_l[lane];
    store_tile(Zb, b_, h, q0B, q, hi, a0, a1, l);
  }
}

// ---------------- 128x128 GEMM: out = Z @ Wo, fp32 epilogue ----------------
__global__ __launch_bounds__(256) void k_gemm_out(const unsigned short* __restrict__ A,
                                                  const unsigned short* __restrict__ Bt,
                                                  float* __restrict__ Out) {
  __shared__ unsigned short As[128 * 32];
  __shared__ unsigned short Bs[128 * 32];
  const int bm = blockIdx.x, bn = blockIdx.y;
  const int tid = threadIdx.x;
  const int lane = tid & 63, wid = tid >> 6;
  const int wr = wid >> 1, wc = wid & 1;
  const int fr = lane & 15, fq = lane >> 4;

  f32x4 acc[4][4];
  #pragma unroll
  for (int i = 0; i < 4; ++i)
    #pragma unroll
    for (int n = 0; n < 4; ++n) acc[i][n] = f32x4{0.f, 0.f, 0.f, 0.f};

  const int arow = tid >> 2, acol = (tid & 3) * 8;
  const int lds0 = tid * 8, lds1 = (tid + 256) * 8;
  const unsigned short* aG0 = A + (bm * 128 + arow) * 1024 + acol;
  const unsigned short* aG1 = A + (bm * 128 + arow + 64) * 1024 + acol;
  const unsigned short* bG0 = Bt + (bn * 128 + arow) * 1024 + acol;
  const unsigned short* bG1 = Bt + (bn * 128 + arow + 64) * 1024 + acol;

  const unsigned short* Ar = As + (wr * 64 + fr) * 32 + fq * 8;
  const unsigned short* Br = Bs + (wc * 64 + fr) * 32 + fq * 8;

  for (int k0 = 0; k0 < 1024; k0 += 32) {
    __syncthreads();
    GLDS16(aG0 + k0, As + lds0);
    GLDS16(aG1 + k0, As + lds1);
    GLDS16(bG0 + k0, Bs + lds0);
    GLDS16(bG1 + k0, Bs + lds1);
    asm volatile("s_waitcnt vmcnt(0)" ::: "memory");
    __syncthreads();
    short8 a[4], b[4];
    #pragma unroll
    for (int i = 0; i < 4; ++i) a[i] = *reinterpret_cast<const short8*>(Ar + i * 512);
    #pragma unroll
    for (int n = 0; n < 4; ++n) b[n] = *reinterpret_cast<const short8*>(Br + n * 512);
    #pragma unroll
    for (int i = 0; i < 4; ++i)
      #pragma unroll
      for (int n = 0; n < 4; ++n)
        acc[i][n] = __builtin_amdgcn_mfma_f32_16x16x32_bf16(a[i], b[n], acc[i][n], 0, 0, 0);
  }

  const int colb = bn * 128 + wc * 64 + fr;
  const int rowb = bm * 128 + wr * 64 + fq * 4;
  #pragma unroll
  for (int n = 0; n < 4; ++n) {
    const int col = colb + n * 16;
    #pragma unroll
    for (int i = 0; i < 4; ++i) {
      const int row = rowb + i * 16;
      #pragma unroll
      for (int j = 0; j < 4; ++j) Out[(row + j) * 1024 + col] = acc[i][n][j];
    }
  }
}

extern "C" void kernel_launch(void* const* d_in, const int* in_sizes, int n_in,
                              void* d_out, int out_size, void* d_ws, size_t ws_size,
                              hipStream_t stream) {
  const float* resid = (const float*)d_in[0];
  const float* w_q = (const float*)d_in[1];
  const float* w_k = (const float*)d_in[2];
  const float* w_v = (const float*)d_in[3];
  const float* w_o = (const float*)d_in[4];
  float* out = (float*)d_out;

  char* ws = (char*)d_ws;
  const size_t MB = 1u << 20;
  unsigned short* Xb = (unsigned short*)(ws);            // 16 MiB: resid bf16; reused as Zb
  unsigned short* W3 = (unsigned short*)(ws + 16 * MB);  // 6 MiB : fused qkv B^T [3072][1024]
  unsigned short* Wo = (unsigned short*)(ws + 22 * MB);  // 2 MiB : WoT [1024][1024]
  unsigned short* Qb = (unsigned short*)(ws + 24 * MB);  // 16 MiB: Q [b][h][s][d] (pre-scaled)
  unsigned short* Kb = (unsigned short*)(ws + 40 * MB);  // 16 MiB: K [b][h][s][d]
  unsigned short* Vt = (unsigned short*)(ws + 56 * MB);  // 16 MiB: V^T [b][h][d][s]
  unsigned short* Zb = Xb;                               // alias: Xb dead after k_gemm_qkv

  hipLaunchKernelGGL(k_cast, dim3(8192), dim3(256), 0, stream, resid, Xb, 8192 * 1024 / 4);
  hipLaunchKernelGGL(k_trans_qkv, dim3(768), dim3(256), 0, stream, w_q, w_k, w_v, W3);
  hipLaunchKernelGGL(k_trans_wo, dim3(256), dim3(256), 0, stream, w_o, Wo);
  hipLaunchKernelGGL(k_gemm_qkv, dim3(64, 24), dim3(256), 0, stream, Xb, W3, Qb, Kb, Vt);
  hipLaunchKernelGGL(k_attn, dim3(2048), dim3(128), 0, stream, Qb, Kb, Vt, Zb);
  hipLaunchKernelGGL(k_gemm_out, dim3(64, 8), dim3(256), 0, stream, Zb, Wo, out);
}

// Round 10
// 248.814 us; speedup vs baseline: 1.0916x; 1.0916x over previous
//
#include <hip/hip_runtime.h>

// Attention_29583734734990 : resid[4,2048,1024] f32, w_q/k/v[16,1024,64], w_o[16,64,1024]
// out[4,2048,1024] f32.  bf16 MFMA pipeline (threshold is bf16-floor 3.14e-2).

typedef __attribute__((ext_vector_type(8))) short short8;
typedef __attribute__((ext_vector_type(4))) float f32x4;
typedef __attribute__((ext_vector_type(16))) float f32x16;

#define GLDS16(g, l) __builtin_amdgcn_global_load_lds(                        \
    (const __attribute__((address_space(1))) unsigned int*)(g),               \
    (__attribute__((address_space(3))) unsigned int*)(l), 16, 0, 0)

static __device__ __forceinline__ unsigned short f2b(float f) {
  union { float f; unsigned u; } c; c.f = f;
  unsigned r = c.u + 0x7fffu + ((c.u >> 16) & 1u);
  return (unsigned short)(r >> 16);
}

// ---------------- cast resid f32 -> bf16, row-major [8192][1024] ----------------
__global__ void k_cast(const float* __restrict__ x, unsigned short* __restrict__ o, int n4) {
  int i = blockIdx.x * blockDim.x + threadIdx.x;
  if (i >= n4) return;
  float4 v = reinterpret_cast<const float4*>(x)[i];
  ushort4 u;
  u.x = f2b(v.x); u.y = f2b(v.y); u.z = f2b(v.z); u.w = f2b(v.w);
  reinterpret_cast<ushort4*>(o)[i] = u;
}

// ---- w_q/w_k/w_v [16][1024][64] f32 -> W3t[(which*1024 + h*64 + d)][1024 m] bf16 ----
__global__ void k_trans_qkv(const float* __restrict__ wq, const float* __restrict__ wk,
                            const float* __restrict__ wv, unsigned short* __restrict__ o) {
  __shared__ float t[64][65];
  int blk = blockIdx.x;            // 3*16*16
  int mt = blk & 15;
  int h = (blk >> 4) & 15;
  int which = blk >> 8;
  const float* w = which == 0 ? wq : (which == 1 ? wk : wv);
  int tid = threadIdx.x;
  int m0 = mt * 64;
  #pragma unroll
  for (int rep = 0; rep < 16; ++rep) {
    int idx = rep * 256 + tid;
    int r = idx >> 6, c = idx & 63;                 // r: m-offset, c: d
    t[r][c] = w[(h * 1024 + m0 + r) * 64 + c];
  }
  __syncthreads();
  #pragma unroll
  for (int rep = 0; rep < 16; ++rep) {
    int idx = rep * 256 + tid;
    int dr = idx >> 6, mc = idx & 63;               // dr: d, mc: m-offset
    o[(which * 1024 + h * 64 + dr) * 1024 + m0 + mc] = f2b(t[mc][dr]);
  }
}

// ---- w_o [1024 k][1024 m] f32 -> WoT[m][k] bf16 ----
__global__ void k_trans_wo(const float* __restrict__ wo, unsigned short* __restrict__ o) {
  __shared__ float t[64][65];
  int blk = blockIdx.x;            // 256
  int mt = blk & 15, kt = blk >> 4;
  int tid = threadIdx.x;
  int k0 = kt * 64, m0 = mt * 64;
  #pragma unroll
  for (int rep = 0; rep < 16; ++rep) {
    int idx = rep * 256 + tid;
    int r = idx >> 6, c = idx & 63;                 // r: k-offset, c: m-offset
    t[r][c] = wo[(k0 + r) * 1024 + m0 + c];
  }
  __syncthreads();
  #pragma unroll
  for (int rep = 0; rep < 16; ++rep) {
    int idx = rep * 256 + tid;
    int r = idx >> 6, c = idx & 63;                 // r: m-offset, c: k-offset
    o[(m0 + r) * 1024 + k0 + c] = f2b(t[c][r]);
  }
}

// ---------------- 128x128 bf16 GEMM -> Q/K/Vt (fused N=3072) ----------------
// Q outputs are PRE-SCALED by 1/sqrt(64)*log2(e) so attention scores are exp2-ready.
__global__ __launch_bounds__(256) void k_gemm_qkv(const unsigned short* __restrict__ A,
                                                  const unsigned short* __restrict__ Bt,
                                                  unsigned short* __restrict__ Qb,
                                                  unsigned short* __restrict__ Kb,
                                                  unsigned short* __restrict__ Vt) {
  __shared__ unsigned short As[128 * 32];
  __shared__ unsigned short Bs[128 * 32];
  const int bm = blockIdx.x, bn = blockIdx.y;
  const int tid = threadIdx.x;
  const int lane = tid & 63, wid = tid >> 6;
  const int wr = wid >> 1, wc = wid & 1;
  const int fr = lane & 15, fq = lane >> 4;

  f32x4 acc[4][4];
  #pragma unroll
  for (int i = 0; i < 4; ++i)
    #pragma unroll
    for (int n = 0; n < 4; ++n) acc[i][n] = f32x4{0.f, 0.f, 0.f, 0.f};

  const int arow = tid >> 2, acol = (tid & 3) * 8;
  const int lds0 = tid * 8, lds1 = (tid + 256) * 8;   // element offsets
  const unsigned short* aG0 = A + (bm * 128 + arow) * 1024 + acol;
  const unsigned short* aG1 = A + (bm * 128 + arow + 64) * 1024 + acol;
  const unsigned short* bG0 = Bt + (bn * 128 + arow) * 1024 + acol;
  const unsigned short* bG1 = Bt + (bn * 128 + arow + 64) * 1024 + acol;

  const unsigned short* Ar = As + (wr * 64 + fr) * 32 + fq * 8;
  const unsigned short* Br = Bs + (wc * 64 + fr) * 32 + fq * 8;

  for (int k0 = 0; k0 < 1024; k0 += 32) {
    __syncthreads();
    GLDS16(aG0 + k0, As + lds0);
    GLDS16(aG1 + k0, As + lds1);
    GLDS16(bG0 + k0, Bs + lds0);
    GLDS16(bG1 + k0, Bs + lds1);
    asm volatile("s_waitcnt vmcnt(0)" ::: "memory");
    __syncthreads();
    short8 a[4], b[4];
    #pragma unroll
    for (int i = 0; i < 4; ++i) a[i] = *reinterpret_cast<const short8*>(Ar + i * 512);
    #pragma unroll
    for (int n = 0; n < 4; ++n) b[n] = *reinterpret_cast<const short8*>(Br + n * 512);
    #pragma unroll
    for (int i = 0; i < 4; ++i)
      #pragma unroll
      for (int n = 0; n < 4; ++n)
        acc[i][n] = __builtin_amdgcn_mfma_f32_16x16x32_bf16(a[i], b[n], acc[i][n], 0, 0, 0);
  }

  const float CS = 0.125f * 1.44269504088896340736f;
  const int colb = bn * 128 + wc * 64 + fr;
  const int rowb = bm * 128 + wr * 64 + fq * 4;
  #pragma unroll
  for (int n = 0; n < 4; ++n) {
    const int col = colb + n * 16;
    const int which = col >> 10, rc = col & 1023;
    const int h = rc >> 6, d = rc & 63;
    #pragma unroll
    for (int i = 0; i < 4; ++i) {
      const int row = rowb + i * 16;
      const int b_ = row >> 11, s = row & 2047;
      if (which == 2) {
        ushort4 v;
        v.x = f2b(acc[i][n][0]); v.y = f2b(acc[i][n][1]);
        v.z = f2b(acc[i][n][2]); v.w = f2b(acc[i][n][3]);
        *reinterpret_cast<ushort4*>(&Vt[(((b_ * 16 + h) * 64) + d) * 2048 + s]) = v;
      } else {
        const float sc = (which == 0) ? CS : 1.f;
        unsigned short* dst = (which == 0 ? Qb : Kb) + ((b_ * 16 + h) * 2048 + s) * 64 + d;
        #pragma unroll
        for (int j = 0; j < 4; ++j) dst[j * 64] = f2b(acc[i][n][j] * sc);
      }
    }
  }
}

// ---------------- causal flash attention, swapped-QK^T 32x32 ----------------
// 2 waves/block share one tile-pair (p, 63-p): wave0 = tileA(p) full [p+1 chunks]
// + tileB first 31-p chunks; wave1 = tileB last 33 chunks. Partials combined via
// LDS after a CONVERGENT __syncthreads (no max-tracking -> pure sum).
// launch_bounds(128,3): VGPR cap 170 >= ~150 live -> NO SPILL, 3 waves/SIMD.

static __device__ __forceinline__ f32x16 mfma32(short8 a, short8 b, f32x16 c) {
  return __builtin_amdgcn_mfma_f32_32x32x16_bf16(a, b, c, 0, 0, 0);
}

struct KV { short8 k0, k1, k2, k3, v0, v1, v2, v3; };

static __device__ __forceinline__ KV load_kv(const unsigned short* __restrict__ Kbh,
                                             const unsigned short* __restrict__ Vbh,
                                             int k0, int q, int hi) {
  KV r;
  const unsigned short* Kp = Kbh + (size_t)(k0 + q) * 64 + hi * 8;
  r.k0 = *reinterpret_cast<const short8*>(Kp);
  r.k1 = *reinterpret_cast<const short8*>(Kp + 16);
  r.k2 = *reinterpret_cast<const short8*>(Kp + 32);
  r.k3 = *reinterpret_cast<const short8*>(Kp + 48);
  const unsigned short* Vp = Vbh + (size_t)q * 2048 + k0 + hi * 8;
  r.v0 = *reinterpret_cast<const short8*>(Vp);
  r.v1 = *reinterpret_cast<const short8*>(Vp + 16);
  r.v2 = *reinterpret_cast<const short8*>(Vp + 32 * 2048);
  r.v3 = *reinterpret_cast<const short8*>(Vp + 32 * 2048 + 16);
  return r;
}

template<bool MASKED>
static __device__ __forceinline__ void tile_step(const KV& kv, int q, int hi,
    const short8& Qf0, const short8& Qf1, const short8& Qf2, const short8& Qf3,
    f32x16& accA, f32x16& accB, float& lsum) {
  f32x16 s = {0.f,0.f,0.f,0.f,0.f,0.f,0.f,0.f,0.f,0.f,0.f,0.f,0.f,0.f,0.f,0.f};
  s = mfma32(kv.k0, Qf0, s);
  s = mfma32(kv.k1, Qf1, s);
  s = mfma32(kv.k2, Qf2, s);
  s = mfma32(kv.k3, Qf3, s);

  float p[16];
  #pragma unroll
  for (int r = 0; r < 16; ++r) {
    if (MASKED) {
      const int kr = (r & 3) + 8 * (r >> 2) + 4 * hi;
      p[r] = (kr <= q) ? __builtin_amdgcn_exp2f(s[r]) : 0.f;
    } else {
      p[r] = __builtin_amdgcn_exp2f(s[r]);
    }
  }
  // tree sum
  float t0 = (p[0] + p[1]) + (p[2] + p[3]);
  float t1 = (p[4] + p[5]) + (p[6] + p[7]);
  float t2 = (p[8] + p[9]) + (p[10] + p[11]);
  float t3 = (p[12] + p[13]) + (p[14] + p[15]);
  lsum += (t0 + t1) + (t2 + t3);

  unsigned W[8], X[8];
  #pragma unroll
  for (int i = 0; i < 8; ++i)
    asm("v_cvt_pk_bf16_f32 %0, %1, %2" : "=v"(W[i]) : "v"(p[2 * i]), "v"(p[2 * i + 1]));
  #pragma unroll
  for (int i = 0; i < 8; ++i) X[i] = __shfl_xor(W[i], 32);

  union { unsigned u[4]; short8 v; } fa0, fa1;
  fa0.u[0] = hi ? X[2] : W[0];
  fa0.u[1] = hi ? X[3] : W[1];
  fa0.u[2] = hi ? W[2] : X[0];
  fa0.u[3] = hi ? W[3] : X[1];
  fa1.u[0] = hi ? X[6] : W[4];
  fa1.u[1] = hi ? X[7] : W[5];
  fa1.u[2] = hi ? W[6] : X[4];
  fa1.u[3] = hi ? W[7] : X[5];

  accA = mfma32(fa0.v, kv.v0, accA);
  accA = mfma32(fa1.v, kv.v1, accA);
  accB = mfma32(fa0.v, kv.v2, accB);
  accB = mfma32(fa1.v, kv.v3, accB);
}

// Process chunks [c0, c0+n) of 32 k each; last chunk optionally causal-masked.
// Rotate-by-2 register prefetch. Requires n >= 1.
template<bool MASK_LAST>
static __device__ __forceinline__ void run_span(
    const unsigned short* __restrict__ Kbh, const unsigned short* __restrict__ Vbh,
    int c0, int n, int q, int hi,
    const short8& Qf0, const short8& Qf1, const short8& Qf2, const short8& Qf3,
    f32x16& a0, f32x16& a1, float& l) {
  const int clast = c0 + n - 1;
  int c = c0;
  KV ca = load_kv(Kbh, Vbh, 32 * c, q, hi);
  while (clast - c >= 2) {
    KV cb = load_kv(Kbh, Vbh, 32 * (c + 1), q, hi);
    tile_step<false>(ca, q, hi, Qf0, Qf1, Qf2, Qf3, a0, a1, l);
    ca = load_kv(Kbh, Vbh, 32 * (c + 2), q, hi);
    tile_step<false>(cb, q, hi, Qf0, Qf1, Qf2, Qf3, a0, a1, l);
    c += 2;
  }
  if (c < clast) {
    KV cb = load_kv(Kbh, Vbh, 32 * (c + 1), q, hi);
    tile_step<false>(ca, q, hi, Qf0, Qf1, Qf2, Qf3, a0, a1, l);
    ca = cb;
    c += 1;
  }
  tile_step<MASK_LAST>(ca, q, hi, Qf0, Qf1, Qf2, Qf3, a0, a1, l);
}

static __device__ __forceinline__ void store_tile(unsigned short* __restrict__ Zb,
    int b_, int h, int q0, int q, int hi,
    const f32x16& a0, const f32x16& a1, float lsum) {
  const float lt = lsum + __shfl_xor(lsum, 32);
  const float rl = 1.f / lt;
  #pragma unroll
  for (int r = 0; r < 16; ++r) {
    const int qr = (r & 3) + 8 * (r >> 2) + 4 * hi;
    const float rlr = __shfl(rl, qr);
    unsigned short* dst = Zb + ((size_t)(b_ * 2048 + q0 + qr)) * 1024 + h * 64 + q;
    dst[0]  = f2b(a0[r] * rlr);
    dst[32] = f2b(a1[r] * rlr);
  }
}

__global__ __launch_bounds__(128, 3) void k_attn(const unsigned short* __restrict__ Qb,
                                                 const unsigned short* __restrict__ Kb,
                                                 const unsigned short* __restrict__ Vt,
                                                 unsigned short* __restrict__ Zb) {
  __shared__ float lds_acc[64][33];
  __shared__ float lds_l[64];
  const int lane = threadIdx.x & 63, w = threadIdx.x >> 6;   // w in {0,1}
  const int q = lane & 31, hi = lane >> 5;
  // XCD-pinned decode: bid%8 = XCD (round-robin); all 32 blocks of a bh share an XCD.
  const int bid = blockIdx.x;                    // 0..2047
  const int bh = (bid & 7) * 8 + ((bid >> 3) & 7);
  const int p = bid >> 6;                        // 0..31 : tile pair index
  const int q0A = 32 * p, q0B = 32 * (63 - p);
  const int b_ = bh >> 4, h = bh & 15;

  const unsigned short* Qbh = Qb + (size_t)bh * 2048 * 64;
  const unsigned short* Kbh = Kb + (size_t)bh * 2048 * 64;
  const unsigned short* Vbh = Vt + (size_t)bh * 64 * 2048;

  const f32x16 zero = {0.f,0.f,0.f,0.f,0.f,0.f,0.f,0.f,0.f,0.f,0.f,0.f,0.f,0.f,0.f,0.f};
  f32x16 a0 = zero, a1 = zero;   // tile-B accumulator (both waves)
  float l = 0.f;

  if (w == 0) {
    // ---- tile A (q0A), full: chunks [0, p] with masked end ----
    {
      const unsigned short* Qp = Qbh + (size_t)(q0A + q) * 64 + hi * 8;
      const short8 Qf0 = *reinterpret_cast<const short8*>(Qp);
      const short8 Qf1 = *reinterpret_cast<const short8*>(Qp + 16);
      const short8 Qf2 = *reinterpret_cast<const short8*>(Qp + 32);
      const short8 Qf3 = *reinterpret_cast<const short8*>(Qp + 48);
      f32x16 aa0 = zero, aa1 = zero;
      float la = 0.f;
      run_span<true>(Kbh, Vbh, 0, p + 1, q, hi, Qf0, Qf1, Qf2, Qf3, aa0, aa1, la);
      store_tile(Zb, b_, h, q0A, q, hi, aa0, aa1, la);
    }
    // ---- tile B (q0B), partial: chunks [0, 31-p), unmasked -> LDS ----
    {
      const unsigned short* Qp = Qbh + (size_t)(q0B + q) * 64 + hi * 8;
      const short8 Qf0 = *reinterpret_cast<const short8*>(Qp);
      const short8 Qf1 = *reinterpret_cast<const short8*>(Qp + 16);
      const short8 Qf2 = *reinterpret_cast<const short8*>(Qp + 32);
      const short8 Qf3 = *reinterpret_cast<const short8*>(Qp + 48);
      const int n = 31 - p;
      if (n > 0)
        run_span<false>(Kbh, Vbh, 0, n, q, hi, Qf0, Qf1, Qf2, Qf3, a0, a1, l);
      #pragma unroll
      for (int i = 0; i < 16; ++i) {
        lds_acc[lane][i] = a0[i];
        lds_acc[lane][16 + i] = a1[i];
      }
      lds_l[lane] = l;
    }
  } else {
    // ---- tile B (q0B), chunks [31-p, 64-p) = 33 chunks, masked end -> regs ----
    const unsigned short* Qp = Qbh + (size_t)(q0B + q) * 64 + hi * 8;
    const short8 Qf0 = *reinterpret_cast<const short8*>(Qp);
    const short8 Qf1 = *reinterpret_cast<const short8*>(Qp + 16);
    const short8 Qf2 = *reinterpret_cast<const short8*>(Qp + 32);
    const short8 Qf3 = *reinterpret_cast<const short8*>(Qp + 48);
    run_span<true>(Kbh, Vbh, 31 - p, 33, q, hi, Qf0, Qf1, Qf2, Qf3, a0, a1, l);
  }

  __syncthreads();   // CONVERGENT barrier: wave0's LDS partials now visible

  if (w == 1) {
    #pragma unroll
    for (int i = 0; i < 16; ++i) {
      a0[i] += lds_acc[lane][i];
      a1[i] += lds_acc[lane][16 + i];
    }
    l += lds_l[lane];
    store_tile(Zb, b_, h, q0B, q, hi, a0, a1, l);
  }
}

// ---------------- 128x128 GEMM: out = Z @ Wo, fp32 epilogue ----------------
__global__ __launch_bounds__(256) void k_gemm_out(const unsigned short* __restrict__ A,
                                                  const unsigned short* __restrict__ Bt,
                                                  float* __restrict__ Out) {
  __shared__ unsigned short As[128 * 32];
  __shared__ unsigned short Bs[128 * 32];
  const int bm = blockIdx.x, bn = blockIdx.y;
  const int tid = threadIdx.x;
  const int lane = tid & 63, wid = tid >> 6;
  const int wr = wid >> 1, wc = wid & 1;
  const int fr = lane & 15, fq = lane >> 4;

  f32x4 acc[4][4];
  #pragma unroll
  for (int i = 0; i < 4; ++i)
    #pragma unroll
    for (int n = 0; n < 4; ++n) acc[i][n] = f32x4{0.f, 0.f, 0.f, 0.f};

  const int arow = tid >> 2, acol = (tid & 3) * 8;
  const int lds0 = tid * 8, lds1 = (tid + 256) * 8;
  const unsigned short* aG0 = A + (bm * 128 + arow) * 1024 + acol;
  const unsigned short* aG1 = A + (bm * 128 + arow + 64) * 1024 + acol;
  const unsigned short* bG0 = Bt + (bn * 128 + arow) * 1024 + acol;
  const unsigned short* bG1 = Bt + (bn * 128 + arow + 64) * 1024 + acol;

  const unsigned short* Ar = As + (wr * 64 + fr) * 32 + fq * 8;
  const unsigned short* Br = Bs + (wc * 64 + fr) * 32 + fq * 8;

  for (int k0 = 0; k0 < 1024; k0 += 32) {
    __syncthreads();
    GLDS16(aG0 + k0, As + lds0);
    GLDS16(aG1 + k0, As + lds1);
    GLDS16(bG0 + k0, Bs + lds0);
    GLDS16(bG1 + k0, Bs + lds1);
    asm volatile("s_waitcnt vmcnt(0)" ::: "memory");
    __syncthreads();
    short8 a[4], b[4];
    #pragma unroll
    for (int i = 0; i < 4; ++i) a[i] = *reinterpret_cast<const short8*>(Ar + i * 512);
    #pragma unroll
    for (int n = 0; n < 4; ++n) b[n] = *reinterpret_cast<const short8*>(Br + n * 512);
    #pragma unroll
    for (int i = 0; i < 4; ++i)
      #pragma unroll
      for (int n = 0; n < 4; ++n)
        acc[i][n] = __builtin_amdgcn_mfma_f32_16x16x32_bf16(a[i], b[n], acc[i][n], 0, 0, 0);
  }

  const int colb = bn * 128 + wc * 64 + fr;
  const int rowb = bm * 128 + wr * 64 + fq * 4;
  #pragma unroll
  for (int n = 0; n < 4; ++n) {
    const int col = colb + n * 16;
    #pragma unroll
    for (int i = 0; i < 4; ++i) {
      const int row = rowb + i * 16;
      #pragma unroll
      for (int j = 0; j < 4; ++j) Out[(row + j) * 1024 + col] = acc[i][n][j];
    }
  }
}

extern "C" void kernel_launch(void* const* d_in, const int* in_sizes, int n_in,
                              void* d_out, int out_size, void* d_ws, size_t ws_size,
                              hipStream_t stream) {
  const float* resid = (const float*)d_in[0];
  const float* w_q = (const float*)d_in[1];
  const float* w_k = (const float*)d_in[2];
  const float* w_v = (const float*)d_in[3];
  const float* w_o = (const float*)d_in[4];
  float* out = (float*)d_out;

  char* ws = (char*)d_ws;
  const size_t MB = 1u << 20;
  unsigned short* Xb = (unsigned short*)(ws);            // 16 MiB: resid bf16; reused as Zb
  unsigned short* W3 = (unsigned short*)(ws + 16 * MB);  // 6 MiB : fused qkv B^T [3072][1024]
  unsigned short* Wo = (unsigned short*)(ws + 22 * MB);  // 2 MiB : WoT [1024][1024]
  unsigned short* Qb = (unsigned short*)(ws + 24 * MB);  // 16 MiB: Q [b][h][s][d] (pre-scaled)
  unsigned short* Kb = (unsigned short*)(ws + 40 * MB);  // 16 MiB: K [b][h][s][d]
  unsigned short* Vt = (unsigned short*)(ws + 56 * MB);  // 16 MiB: V^T [b][h][d][s]
  unsigned short* Zb = Xb;                               // alias: Xb dead after k_gemm_qkv

  hipLaunchKernelGGL(k_cast, dim3(8192), dim3(256), 0, stream, resid, Xb, 8192 * 1024 / 4);
  hipLaunchKernelGGL(k_trans_qkv, dim3(768), dim3(256), 0, stream, w_q, w_k, w_v, W3);
  hipLaunchKernelGGL(k_trans_wo, dim3(256), dim3(256), 0, stream, w_o, Wo);
  hipLaunchKernelGGL(k_gemm_qkv, dim3(64, 24), dim3(256), 0, stream, Xb, W3, Qb, Kb, Vt);
  hipLaunchKernelGGL(k_attn, dim3(2048), dim3(128), 0, stream, Qb, Kb, Vt, Zb);
  hipLaunchKernelGGL(k_gemm_out, dim3(64, 8), dim3(256), 0, stream, Zb, Wo, out);
}

// Round 11
// 183.842 us; speedup vs baseline: 1.4774x; 1.3534x over previous
//
#include <hip/hip_runtime.h>

// Attention_29583734734990 : resid[4,2048,1024] f32, w_q/k/v[16,1024,64], w_o[16,64,1024]
// out[4,2048,1024] f32.  bf16 MFMA pipeline (threshold is bf16-floor 3.14e-2).

typedef __attribute__((ext_vector_type(8))) short short8;
typedef __attribute__((ext_vector_type(4))) float f32x4;
typedef __attribute__((ext_vector_type(16))) float f32x16;

#define GLDS16(g, l) __builtin_amdgcn_global_load_lds(                        \
    (const __attribute__((address_space(1))) unsigned int*)(g),               \
    (__attribute__((address_space(3))) unsigned int*)(l), 16, 0, 0)

static __device__ __forceinline__ unsigned short f2b(float f) {
  union { float f; unsigned u; } c; c.f = f;
  unsigned r = c.u + 0x7fffu + ((c.u >> 16) & 1u);
  return (unsigned short)(r >> 16);
}

// ---------------- cast resid f32 -> bf16, row-major [8192][1024] ----------------
__global__ void k_cast(const float* __restrict__ x, unsigned short* __restrict__ o, int n4) {
  int i = blockIdx.x * blockDim.x + threadIdx.x;
  if (i >= n4) return;
  float4 v = reinterpret_cast<const float4*>(x)[i];
  ushort4 u;
  u.x = f2b(v.x); u.y = f2b(v.y); u.z = f2b(v.z); u.w = f2b(v.w);
  reinterpret_cast<ushort4*>(o)[i] = u;
}

// ---- w_q/w_k/w_v [16][1024][64] f32 -> W3t[(which*1024 + h*64 + d)][1024 m] bf16 ----
__global__ void k_trans_qkv(const float* __restrict__ wq, const float* __restrict__ wk,
                            const float* __restrict__ wv, unsigned short* __restrict__ o) {
  __shared__ float t[64][65];
  int blk = blockIdx.x;            // 3*16*16
  int mt = blk & 15;
  int h = (blk >> 4) & 15;
  int which = blk >> 8;
  const float* w = which == 0 ? wq : (which == 1 ? wk : wv);
  int tid = threadIdx.x;
  int m0 = mt * 64;
  #pragma unroll
  for (int rep = 0; rep < 16; ++rep) {
    int idx = rep * 256 + tid;
    int r = idx >> 6, c = idx & 63;
    t[r][c] = w[(h * 1024 + m0 + r) * 64 + c];
  }
  __syncthreads();
  #pragma unroll
  for (int rep = 0; rep < 16; ++rep) {
    int idx = rep * 256 + tid;
    int dr = idx >> 6, mc = idx & 63;
    o[(which * 1024 + h * 64 + dr) * 1024 + m0 + mc] = f2b(t[mc][dr]);
  }
}

// ---- w_o [1024 k][1024 m] f32 -> WoT[m][k] bf16 ----
__global__ void k_trans_wo(const float* __restrict__ wo, unsigned short* __restrict__ o) {
  __shared__ float t[64][65];
  int blk = blockIdx.x;            // 256
  int mt = blk & 15, kt = blk >> 4;
  int tid = threadIdx.x;
  int k0 = kt * 64, m0 = mt * 64;
  #pragma unroll
  for (int rep = 0; rep < 16; ++rep) {
    int idx = rep * 256 + tid;
    int r = idx >> 6, c = idx & 63;
    t[r][c] = wo[(k0 + r) * 1024 + m0 + c];
  }
  __syncthreads();
  #pragma unroll
  for (int rep = 0; rep < 16; ++rep) {
    int idx = rep * 256 + tid;
    int r = idx >> 6, c = idx & 63;
    o[(m0 + r) * 1024 + k0 + c] = f2b(t[c][r]);
  }
}

// ---------------- 128x128 bf16 GEMM -> Q / Kc / Vc (fused N=3072) ----------------
// Q [bh][s][64] PRE-SCALED by 1/sqrt(64)*log2(e).
// Kc: per (bh, chunk c=s>>5) contiguous 4KB blob [r=s&31][64 d], d slot-swizzled:
//     element (r,d) stored at col (((d>>3) ^ (r&7))<<3) | (d&7).
// Vc: per (bh, c) 4KB blob of 32 macro-rows (r=d>>1) x 128B; element (d, kk=s&31)
//     stored at r*64 + ((((d&1)*4 + (kk>>3)) ^ (r&7))<<3) + (kk&7).
__global__ __launch_bounds__(256) void k_gemm_qkv(const unsigned short* __restrict__ A,
                                                  const unsigned short* __restrict__ Bt,
                                                  unsigned short* __restrict__ Qb,
                                                  unsigned short* __restrict__ Kc,
                                                  unsigned short* __restrict__ Vc) {
  __shared__ unsigned short As[128 * 32];
  __shared__ unsigned short Bs[128 * 32];
  const int bm = blockIdx.x, bn = blockIdx.y;
  const int tid = threadIdx.x;
  const int lane = tid & 63, wid = tid >> 6;
  const int wr = wid >> 1, wc = wid & 1;
  const int fr = lane & 15, fq = lane >> 4;

  f32x4 acc[4][4];
  #pragma unroll
  for (int i = 0; i < 4; ++i)
    #pragma unroll
    for (int n = 0; n < 4; ++n) acc[i][n] = f32x4{0.f, 0.f, 0.f, 0.f};

  const int arow = tid >> 2, acol = (tid & 3) * 8;
  const int lds0 = tid * 8, lds1 = (tid + 256) * 8;
  const unsigned short* aG0 = A + (bm * 128 + arow) * 1024 + acol;
  const unsigned short* aG1 = A + (bm * 128 + arow + 64) * 1024 + acol;
  const unsigned short* bG0 = Bt + (bn * 128 + arow) * 1024 + acol;
  const unsigned short* bG1 = Bt + (bn * 128 + arow + 64) * 1024 + acol;

  const unsigned short* Ar = As + (wr * 64 + fr) * 32 + fq * 8;
  const unsigned short* Br = Bs + (wc * 64 + fr) * 32 + fq * 8;

  for (int k0 = 0; k0 < 1024; k0 += 32) {
    __syncthreads();
    GLDS16(aG0 + k0, As + lds0);
    GLDS16(aG1 + k0, As + lds1);
    GLDS16(bG0 + k0, Bs + lds0);
    GLDS16(bG1 + k0, Bs + lds1);
    asm volatile("s_waitcnt vmcnt(0)" ::: "memory");
    __syncthreads();
    short8 a[4], b[4];
    #pragma unroll
    for (int i = 0; i < 4; ++i) a[i] = *reinterpret_cast<const short8*>(Ar + i * 512);
    #pragma unroll
    for (int n = 0; n < 4; ++n) b[n] = *reinterpret_cast<const short8*>(Br + n * 512);
    #pragma unroll
    for (int i = 0; i < 4; ++i)
      #pragma unroll
      for (int n = 0; n < 4; ++n)
        acc[i][n] = __builtin_amdgcn_mfma_f32_16x16x32_bf16(a[i], b[n], acc[i][n], 0, 0, 0);
  }

  const float CS = 0.125f * 1.44269504088896340736f;
  const int colb = bn * 128 + wc * 64 + fr;
  const int rowb = bm * 128 + wr * 64 + fq * 4;
  #pragma unroll
  for (int n = 0; n < 4; ++n) {
    const int col = colb + n * 16;
    const int which = col >> 10, rc = col & 1023;
    const int h = rc >> 6, d = rc & 63;
    #pragma unroll
    for (int i = 0; i < 4; ++i) {
      const int row = rowb + i * 16;
      const int b_ = row >> 11, s = row & 2047;
      const int bh = b_ * 16 + h;
      if (which == 2) {
        const int c = s >> 5, kk = s & 31;
        const int r = d >> 1;
        const int sl = (((d & 1) * 4 + (kk >> 3)) ^ (r & 7));
        ushort4 v;
        v.x = f2b(acc[i][n][0]); v.y = f2b(acc[i][n][1]);
        v.z = f2b(acc[i][n][2]); v.w = f2b(acc[i][n][3]);
        *reinterpret_cast<ushort4*>(
            &Vc[((size_t)(bh * 64 + c)) * 2048 + r * 64 + sl * 8 + (kk & 7)]) = v;
      } else if (which == 1) {
        #pragma unroll
        for (int j = 0; j < 4; ++j) {
          const int ss = s + j;
          const int c = ss >> 5, r = ss & 31;
          const int dsw = (((d >> 3) ^ (r & 7)) << 3) | (d & 7);
          Kc[(((size_t)(bh * 64 + c)) * 32 + r) * 64 + dsw] = f2b(acc[i][n][j]);
        }
      } else {
        unsigned short* dst = Qb + ((size_t)bh * 2048 + s) * 64 + d;
        #pragma unroll
        for (int j = 0; j < 4; ++j) dst[j * 64] = f2b(acc[i][n][j] * CS);
      }
    }
  }
}

// ---------------- causal flash attention, LDS-staged K/V, swapped-QK^T 32x32 ----------------
// Block = 4 waves = 128-row q-supertile. Pair (P, 15-P) -> uniform 68 chunks/block.
// Per chunk: 2 linear global_load_lds (4KB K + 4KB V, pre-swizzled blobs), dbuf,
// counted vmcnt(2); all 4 waves share the staged chunk. Convergent barriers only.

static __device__ __forceinline__ f32x16 mfma32(short8 a, short8 b, f32x16 c) {
  return __builtin_amdgcn_mfma_f32_32x32x16_bf16(a, b, c, 0, 0, 0);
}

template<bool MASKED>
static __device__ __forceinline__ void compute_chunk(
    const unsigned short* __restrict__ Kl, const unsigned short* __restrict__ Vl,
    int q, int hi,
    const short8& Qf0, const short8& Qf1, const short8& Qf2, const short8& Qf3,
    f32x16& accA, f32x16& accB, float& lsum) {
  const int qs = q & 7;
  const short8 kf0 = *reinterpret_cast<const short8*>(Kl + q * 64 + (((0 + hi) ^ qs) << 3));
  const short8 kf1 = *reinterpret_cast<const short8*>(Kl + q * 64 + (((2 + hi) ^ qs) << 3));
  const short8 kf2 = *reinterpret_cast<const short8*>(Kl + q * 64 + (((4 + hi) ^ qs) << 3));
  const short8 kf3 = *reinterpret_cast<const short8*>(Kl + q * 64 + (((6 + hi) ^ qs) << 3));
  const int vr = q >> 1, vs = (q & 1) * 4, vw = vr & 7;
  const short8 v00 = *reinterpret_cast<const short8*>(Vl + vr * 64 + (((vs + hi) ^ vw) << 3));
  const short8 v01 = *reinterpret_cast<const short8*>(Vl + vr * 64 + (((vs + 2 + hi) ^ vw) << 3));
  const short8 v10 = *reinterpret_cast<const short8*>(Vl + (vr + 16) * 64 + (((vs + hi) ^ vw) << 3));
  const short8 v11 = *reinterpret_cast<const short8*>(Vl + (vr + 16) * 64 + (((vs + 2 + hi) ^ vw) << 3));

  f32x16 s = {0.f,0.f,0.f,0.f,0.f,0.f,0.f,0.f,0.f,0.f,0.f,0.f,0.f,0.f,0.f,0.f};
  s = mfma32(kf0, Qf0, s);
  s = mfma32(kf1, Qf1, s);
  s = mfma32(kf2, Qf2, s);
  s = mfma32(kf3, Qf3, s);

  float p[16];
  #pragma unroll
  for (int r = 0; r < 16; ++r) {
    if (MASKED) {
      const int kr = (r & 3) + 8 * (r >> 2) + 4 * hi;
      p[r] = (kr <= q) ? __builtin_amdgcn_exp2f(s[r]) : 0.f;
    } else {
      p[r] = __builtin_amdgcn_exp2f(s[r]);
    }
  }
  float t0 = (p[0] + p[1]) + (p[2] + p[3]);
  float t1 = (p[4] + p[5]) + (p[6] + p[7]);
  float t2 = (p[8] + p[9]) + (p[10] + p[11]);
  float t3 = (p[12] + p[13]) + (p[14] + p[15]);
  lsum += (t0 + t1) + (t2 + t3);

  unsigned W[8], X[8];
  #pragma unroll
  for (int i = 0; i < 8; ++i)
    asm("v_cvt_pk_bf16_f32 %0, %1, %2" : "=v"(W[i]) : "v"(p[2 * i]), "v"(p[2 * i + 1]));
  #pragma unroll
  for (int i = 0; i < 8; ++i) X[i] = __shfl_xor(W[i], 32);

  union { unsigned u[4]; short8 v; } fa0, fa1;
  fa0.u[0] = hi ? X[2] : W[0];
  fa0.u[1] = hi ? X[3] : W[1];
  fa0.u[2] = hi ? W[2] : X[0];
  fa0.u[3] = hi ? W[3] : X[1];
  fa1.u[0] = hi ? X[6] : W[4];
  fa1.u[1] = hi ? X[7] : W[5];
  fa1.u[2] = hi ? W[6] : X[4];
  fa1.u[3] = hi ? W[7] : X[5];

  accA = mfma32(fa0.v, v00, accA);
  accA = mfma32(fa1.v, v01, accA);
  accB = mfma32(fa0.v, v10, accB);
  accB = mfma32(fa1.v, v11, accB);
}

static __device__ __forceinline__ void store_tile(unsigned short* __restrict__ Zb,
    int b_, int h, int q0, int q, int hi,
    const f32x16& a0, const f32x16& a1, float lsum) {
  const float lt = lsum + __shfl_xor(lsum, 32);
  const float rl = 1.f / lt;
  #pragma unroll
  for (int r = 0; r < 16; ++r) {
    const int qr = (r & 3) + 8 * (r >> 2) + 4 * hi;
    const float rlr = __shfl(rl, qr);
    unsigned short* dst = Zb + ((size_t)(b_ * 2048 + q0 + qr)) * 1024 + h * 64 + q;
    dst[0]  = f2b(a0[r] * rlr);
    dst[32] = f2b(a1[r] * rlr);
  }
}

__global__ __launch_bounds__(256, 2) void k_attn(const unsigned short* __restrict__ Qb,
                                                 const unsigned short* __restrict__ Kc,
                                                 const unsigned short* __restrict__ Vc,
                                                 unsigned short* __restrict__ Zb) {
  __shared__ __align__(16) unsigned short Kbuf[2][2048];
  __shared__ __align__(16) unsigned short Vbuf[2][2048];
  const int tid = threadIdx.x;
  const int lane = tid & 63, w = tid >> 6;
  const int q = lane & 31, hi = lane >> 5;
  // XCD-pinned: bid%8 = XCD; all 8 blocks of one bh share an XCD.
  const int bid = blockIdx.x;                    // 0..511
  const int bh = (bid & 7) * 8 + ((bid >> 3) & 7);
  const int P1 = bid >> 6;                       // 0..7 -> pair (P1, 15-P1)
  const int b_ = bh >> 4, h = bh & 15;

  const unsigned short* Qbh = Qb + (size_t)bh * 2048 * 64;
  const unsigned short* Kch = Kc + (size_t)bh * 64 * 2048;
  const unsigned short* Vch = Vc + (size_t)bh * 64 * 2048;

  #pragma unroll 1
  for (int t = 0; t < 2; ++t) {
    const int P = t ? (15 - P1) : P1;
    const int q0 = 128 * P + 32 * w;
    const int cmax = 4 * P + w;
    const int C = 4 * P + 4;

    const unsigned short* Qp = Qbh + (size_t)(q0 + q) * 64 + hi * 8;
    const short8 Qf0 = *reinterpret_cast<const short8*>(Qp);
    const short8 Qf1 = *reinterpret_cast<const short8*>(Qp + 16);
    const short8 Qf2 = *reinterpret_cast<const short8*>(Qp + 32);
    const short8 Qf3 = *reinterpret_cast<const short8*>(Qp + 48);

    f32x16 a0 = {0.f,0.f,0.f,0.f,0.f,0.f,0.f,0.f,0.f,0.f,0.f,0.f,0.f,0.f,0.f,0.f};
    f32x16 a1 = a0;
    float l = 0.f;

    // stage chunk 0 (linear 4KB memcpy x2, fully coalesced)
    GLDS16(Kch + tid * 8, &Kbuf[0][tid * 8]);
    GLDS16(Vch + tid * 8, &Vbuf[0][tid * 8]);

    for (int c = 0; c < C; ++c) {
      if (c + 1 < C) {
        const int par = (c + 1) & 1;
        GLDS16(Kch + (size_t)(c + 1) * 2048 + tid * 8, &Kbuf[par][tid * 8]);
        GLDS16(Vch + (size_t)(c + 1) * 2048 + tid * 8, &Vbuf[par][tid * 8]);
        asm volatile("s_waitcnt vmcnt(2)" ::: "memory");   // chunk-c's 2 ops done
      } else {
        asm volatile("s_waitcnt vmcnt(0)" ::: "memory");
      }
      __syncthreads();                                     // staged chunk visible block-wide
      if (c <= cmax) {
        const int par = c & 1;
        if (c == cmax)
          compute_chunk<true>(Kbuf[par], Vbuf[par], q, hi, Qf0, Qf1, Qf2, Qf3, a0, a1, l);
        else
          compute_chunk<false>(Kbuf[par], Vbuf[par], q, hi, Qf0, Qf1, Qf2, Qf3, a0, a1, l);
      }
      __syncthreads();                                     // all reads done before overwrite
    }
    store_tile(Zb, b_, h, q0, q, hi, a0, a1, l);
  }
}

// ---------------- 128x128 GEMM: out = Z @ Wo, fp32 epilogue ----------------
__global__ __launch_bounds__(256) void k_gemm_out(const unsigned short* __restrict__ A,
                                                  const unsigned short* __restrict__ Bt,
                                                  float* __restrict__ Out) {
  __shared__ unsigned short As[128 * 32];
  __shared__ unsigned short Bs[128 * 32];
  const int bm = blockIdx.x, bn = blockIdx.y;
  const int tid = threadIdx.x;
  const int lane = tid & 63, wid = tid >> 6;
  const int wr = wid >> 1, wc = wid & 1;
  const int fr = lane & 15, fq = lane >> 4;

  f32x4 acc[4][4];
  #pragma unroll
  for (int i = 0; i < 4; ++i)
    #pragma unroll
    for (int n = 0; n < 4; ++n) acc[i][n] = f32x4{0.f, 0.f, 0.f, 0.f};

  const int arow = tid >> 2, acol = (tid & 3) * 8;
  const int lds0 = tid * 8, lds1 = (tid + 256) * 8;
  const unsigned short* aG0 = A + (bm * 128 + arow) * 1024 + acol;
  const unsigned short* aG1 = A + (bm * 128 + arow + 64) * 1024 + acol;
  const unsigned short* bG0 = Bt + (bn * 128 + arow) * 1024 + acol;
  const unsigned short* bG1 = Bt + (bn * 128 + arow + 64) * 1024 + acol;

  const unsigned short* Ar = As + (wr * 64 + fr) * 32 + fq * 8;
  const unsigned short* Br = Bs + (wc * 64 + fr) * 32 + fq * 8;

  for (int k0 = 0; k0 < 1024; k0 += 32) {
    __syncthreads();
    GLDS16(aG0 + k0, As + lds0);
    GLDS16(aG1 + k0, As + lds1);
    GLDS16(bG0 + k0, Bs + lds0);
    GLDS16(bG1 + k0, Bs + lds1);
    asm volatile("s_waitcnt vmcnt(0)" ::: "memory");
    __syncthreads();
    short8 a[4], b[4];
    #pragma unroll
    for (int i = 0; i < 4; ++i) a[i] = *reinterpret_cast<const short8*>(Ar + i * 512);
    #pragma unroll
    for (int n = 0; n < 4; ++n) b[n] = *reinterpret_cast<const short8*>(Br + n * 512);
    #pragma unroll
    for (int i = 0; i < 4; ++i)
      #pragma unroll
      for (int n = 0; n < 4; ++n)
        acc[i][n] = __builtin_amdgcn_mfma_f32_16x16x32_bf16(a[i], b[n], acc[i][n], 0, 0, 0);
  }

  const int colb = bn * 128 + wc * 64 + fr;
  const int rowb = bm * 128 + wr * 64 + fq * 4;
  #pragma unroll
  for (int n = 0; n < 4; ++n) {
    const int col = colb + n * 16;
    #pragma unroll
    for (int i = 0; i < 4; ++i) {
      const int row = rowb + i * 16;
      #pragma unroll
      for (int j = 0; j < 4; ++j) Out[(row + j) * 1024 + col] = acc[i][n][j];
    }
  }
}

extern "C" void kernel_launch(void* const* d_in, const int* in_sizes, int n_in,
                              void* d_out, int out_size, void* d_ws, size_t ws_size,
                              hipStream_t stream) {
  const float* resid = (const float*)d_in[0];
  const float* w_q = (const float*)d_in[1];
  const float* w_k = (const float*)d_in[2];
  const float* w_v = (const float*)d_in[3];
  const float* w_o = (const float*)d_in[4];
  float* out = (float*)d_out;

  char* ws = (char*)d_ws;
  const size_t MB = 1u << 20;
  unsigned short* Xb = (unsigned short*)(ws);            // 16 MiB: resid bf16; reused as Zb
  unsigned short* W3 = (unsigned short*)(ws + 16 * MB);  // 6 MiB : fused qkv B^T [3072][1024]
  unsigned short* Wo = (unsigned short*)(ws + 22 * MB);  // 2 MiB : WoT [1024][1024]
  unsigned short* Qb = (unsigned short*)(ws + 24 * MB);  // 16 MiB: Q [bh][s][d] (pre-scaled)
  unsigned short* Kc = (unsigned short*)(ws + 40 * MB);  // 16 MiB: K chunked+swizzled blobs
  unsigned short* Vc = (unsigned short*)(ws + 56 * MB);  // 16 MiB: V chunked+swizzled blobs
  unsigned short* Zb = Xb;                               // alias: Xb dead after k_gemm_qkv

  hipLaunchKernelGGL(k_cast, dim3(8192), dim3(256), 0, stream, resid, Xb, 8192 * 1024 / 4);
  hipLaunchKernelGGL(k_trans_qkv, dim3(768), dim3(256), 0, stream, w_q, w_k, w_v, W3);
  hipLaunchKernelGGL(k_trans_wo, dim3(256), dim3(256), 0, stream, w_o, Wo);
  hipLaunchKernelGGL(k_gemm_qkv, dim3(64, 24), dim3(256), 0, stream, Xb, W3, Qb, Kc, Vc);
  hipLaunchKernelGGL(k_attn, dim3(512), dim3(256), 0, stream, Qb, Kc, Vc, Zb);
  hipLaunchKernelGGL(k_gemm_out, dim3(64, 8), dim3(256), 0, stream, Zb, Wo, out);
}